// Round 9
// baseline (3480.426 us; speedup 1.0000x reference)
//
#include <hip/hip_runtime.h>
#include <hip/hip_bf16.h>
#include <cstdint>
#include <cstddef>

// ---------------------------------------------------------------------------
// MultilayerGRU: emb-gather -> GRU(256->512) -> GRU(512->512) -> FC(512->128)
//                -> log_softmax.   B=32, S=512, DI=256, DH=512, DO=128
//
// Round-9: r8 layer-pipelined dataflow + minimum-latency hops:
//  - all poll loads of a wait issued concurrently (1 RTT, not 2-4)
//  - publishes are 2B agent-atomic stores straight from gate registers,
//    BEFORE any barrier (no LDS staging round-trip); consumers tolerate
//    torn chunks via per-short sentinel checks (values are write-once)
//  - 3 barriers/step instead of 4
// Proven base: sentinel dataflow (r7), fused pipeline (r8); cross-WG data
// only via compiler-emitted relaxed AGENT atomics (r1-r7 evidence).
// ---------------------------------------------------------------------------

typedef short v8ss __attribute__((ext_vector_type(8)));     // 8 bf16 (4 VGPR)
typedef float v4f  __attribute__((ext_vector_type(4)));
typedef unsigned short u16x8 __attribute__((ext_vector_type(8)));
typedef unsigned long long u64;

#define MFMA16(a, b, c) __builtin_amdgcn_mfma_f32_16x16x32_bf16((a), (b), (c), 0, 0, 0)

__device__ __forceinline__ unsigned short f2bf(float f) {
  union { float f; unsigned u; } v; v.f = f;
  unsigned r = v.u + 0x7fffu + ((v.u >> 16) & 1u);   // RNE
  return (unsigned short)(r >> 16);
}
// published values must never equal the sentinel bf16 pattern 0x8080
__device__ __forceinline__ unsigned short f2bfp(float f) {
  unsigned short h = f2bf(f);
  return (h == 0x8080u) ? (unsigned short)0x8081u : h;   // |delta| ~ 1e-38
}
__device__ __forceinline__ float bf2f(unsigned short h) {
  union { unsigned u; float f; } v; v.u = ((unsigned)h) << 16; return v.f;
}

#define S64   0x8080808080808080ull
#define INF64 0x7F807F807F807F80ull
#define POLL_LIM 16384

__device__ __forceinline__ u64 aload(const u64* p) {
  return __hip_atomic_load(p, __ATOMIC_RELAXED, __HIP_MEMORY_SCOPE_AGENT);
}
__device__ __forceinline__ void astore(u64* p, u64 v) {
  __hip_atomic_store(p, v, __ATOMIC_RELAXED, __HIP_MEMORY_SCOPE_AGENT);
}
__device__ __forceinline__ void astore16(unsigned short* p, unsigned short v) {
  __hip_atomic_store(p, v, __ATOMIC_RELAXED, __HIP_MEMORY_SCOPE_AGENT);
}
// any 16-bit lane of x equal to zero?  (x = v ^ S64 -> sentinel detect)
__device__ __forceinline__ int hz16(u64 x) {
  return ((x - 0x0001000100010001ull) & ~x & 0x8000800080008000ull) != 0ull;
}
// concurrent poll of 2 consecutive 8B chunks (per-short sentinel checks)
__device__ __forceinline__ void spin2(const u64* p, u64* o, int* dead) {
  u64 a = aload(p), b = aload(p + 1);
  int it = 0;
  while (hz16(a ^ S64) | hz16(b ^ S64)) {
    if (*(volatile int*)dead) break;
    if (++it > POLL_LIM) { *(volatile int*)dead = 1; break; }
    __builtin_amdgcn_s_sleep(1);
    a = aload(p); b = aload(p + 1);
  }
  o[0] = a; o[1] = b;
}
// concurrent poll of 4 consecutive 8B chunks
__device__ __forceinline__ void spin4(const u64* p, u64* o, int* dead) {
  u64 a = aload(p), b = aload(p + 1), c = aload(p + 2), d = aload(p + 3);
  int it = 0;
  while (hz16(a ^ S64) | hz16(b ^ S64) | hz16(c ^ S64) | hz16(d ^ S64)) {
    if (*(volatile int*)dead) break;
    if (++it > POLL_LIM) { *(volatile int*)dead = 1; break; }
    __builtin_amdgcn_s_sleep(1);
    a = aload(p); b = aload(p + 1); c = aload(p + 2); d = aload(p + 3);
  }
  o[0] = a; o[1] = b; o[2] = c; o[3] = d;
}
// concurrent poll of 2+2 chunks at two bases (L1: x-input + own h in one wait)
__device__ __forceinline__ void spin22(const u64* p, const u64* q, u64* o, int* dead) {
  u64 a = aload(p), b = aload(p + 1), c = aload(q), d = aload(q + 1);
  int it = 0;
  while (hz16(a ^ S64) | hz16(b ^ S64) | hz16(c ^ S64) | hz16(d ^ S64)) {
    if (*(volatile int*)dead) break;
    if (++it > POLL_LIM) { *(volatile int*)dead = 1; break; }
    __builtin_amdgcn_s_sleep(1);
    a = aload(p); b = aload(p + 1); c = aload(q); d = aload(q + 1);
  }
  o[0] = a; o[1] = b; o[2] = c; o[3] = d;
}

// ----- sizes -----
#define BB   32
#define SS   512
#define DI   256
#define DH   512
#define DO   128
#define MROWS (BB * SS)          // 16384, row index = t*32 + b
#define SLAB 16384               // elems per time-slot: 32 batches x 512

// ----- ws offsets (bytes); total ~81.2 MB -----
#define O_HX0   0                              // [513][32][512] bf16
#define O_HX1   16809984                       // [513][32][512] bf16
#define O_RHX0  33619968                       // [512][32][512] bf16
#define O_RHX1  50397184                       // [512][32][512] bf16
#define O_WT0X  67174400                       // [1536][256] bf16 (streamed)
#define O_WT0H  (O_WT0X + 1536*256*2)          // [16][96][512] bf16
#define O_WT1X  (O_WT0H + 16*96*512*2)         // [1536][512] bf16 (streamed)
#define O_WT1H  (O_WT1X + 1536*512*2)          // [16][96][512] bf16
#define O_WTFC  (O_WT1H + 16*96*512*2)         // [128][512] bf16
#define O_XEMB  (O_WTFC + 128*512*2)           // [16384][256] bf16

// ---------------------------------------------------------------------------
// weight repack: f32 -> bf16 transposed layouts
// ---------------------------------------------------------------------------
__global__ void prep_kernel(const float* __restrict__ l0Wz, const float* __restrict__ l0Wr,
                            const float* __restrict__ l0Wn,
                            const float* __restrict__ l1Wz, const float* __restrict__ l1Wr,
                            const float* __restrict__ l1Wn,
                            const float* __restrict__ fcW,
                            unsigned short* __restrict__ Wt0x, unsigned short* __restrict__ Wt0h,
                            unsigned short* __restrict__ Wt1x, unsigned short* __restrict__ Wt1h,
                            unsigned short* __restrict__ WtFC) {
  const int n0 = 1536 * 256;        // Wt0x
  const int n1 = 16 * 96 * 512;     // Wt0h
  const int n2 = 1536 * 512;        // Wt1x
  const int n3 = 16 * 96 * 512;     // Wt1h
  const int n4 = 128 * 512;         // WtFC
  const int total = n0 + n1 + n2 + n3 + n4;
  for (int i = blockIdx.x * 256 + threadIdx.x; i < total; i += gridDim.x * 256) {
    int j = i;
    if (j < n0) {  // Wt0x[gcol][k] = l0_W{g}[k][c]
      int gcol = j / 256, k = j % 256, g = gcol >> 9, c = gcol & 511;
      const float* W = g == 0 ? l0Wz : (g == 1 ? l0Wr : l0Wn);
      Wt0x[j] = f2bf(W[k * 512 + c]); continue;
    }
    j -= n0;
    if (j < n1) {  // Wt0h[r][row][k] = l0_W{g(row)}[256+k][r*32 + (row&31)]
      int r = j / (96 * 512), rem = j % (96 * 512), row = rem / 512, k = rem % 512;
      int g = row >> 5, c = r * 32 + (row & 31);
      const float* W = g == 0 ? l0Wz : (g == 1 ? l0Wr : l0Wn);
      Wt0h[j] = f2bf(W[(256 + k) * 512 + c]); continue;
    }
    j -= n1;
    if (j < n2) {  // Wt1x[gcol][k] = l1_W{g}[k][c]
      int gcol = j / 512, k = j % 512, g = gcol >> 9, c = gcol & 511;
      const float* W = g == 0 ? l1Wz : (g == 1 ? l1Wr : l1Wn);
      Wt1x[j] = f2bf(W[k * 512 + c]); continue;
    }
    j -= n2;
    if (j < n3) {  // Wt1h[r][row][k] = l1_W{g(row)}[512+k][r*32 + (row&31)]
      int r = j / (96 * 512), rem = j % (96 * 512), row = rem / 512, k = rem % 512;
      int g = row >> 5, c = r * 32 + (row & 31);
      const float* W = g == 0 ? l1Wz : (g == 1 ? l1Wr : l1Wn);
      Wt1h[j] = f2bf(W[(512 + k) * 512 + c]); continue;
    }
    j -= n3;
    { int c = j / 512, k = j % 512; WtFC[j] = f2bf(fcW[k * 128 + c]); }
  }
}

// ---------------------------------------------------------------------------
// embedding gather
// ---------------------------------------------------------------------------
__global__ void embed_kernel(const int* __restrict__ tokens, const float* __restrict__ emb,
                             unsigned short* __restrict__ Xemb) {
  int r = blockIdx.x;            // 0..16383  (t-major)
  int c = threadIdx.x;           // 0..255
  int t = r >> 5, b = r & 31;
  int tok = tokens[b * SS + t];
  Xemb[(size_t)r * DI + c] = f2bf(emb[(size_t)tok * DI + c]);
}

// ---------------------------------------------------------------------------
// fused pipelined GRU body (one layer instance per WG).
// group g owns batches 4g..4g+3; role owns h-cols 32r..32r+31.
// ---------------------------------------------------------------------------
template <int LAYER>
__device__ __forceinline__ void gru_body(
    const int g, const int role, const int tid,
    const unsigned short* __restrict__ WtH,   // [16][96][512]
    const unsigned short* __restrict__ Wx,    // [1536][K]
    const unsigned short* __restrict__ Xe,    // Xemb (L0 only)
    unsigned short* hx0,                      // x-source slabs (L1 only)
    unsigned short* hx, unsigned short* rhx,
    const float* __restrict__ bz, const float* __restrict__ br,
    const float* __restrict__ bn,
    unsigned short* Wt, unsigned short* At, unsigned short* Rt, unsigned short* Xt,
    float* zbuf, float* hbuf, int* dead) {
  constexpr int K = LAYER ? 512 : 256;

  // recurrent-weight slice -> LDS (96 rows x 512)
  for (int ch = tid; ch < 96 * 64; ch += 256) {
    int row = ch >> 6, off = (ch & 63) * 8;
    *(u16x8*)&Wt[row * 520 + off] = *(const u16x8*)&WtH[((size_t)role * 96 + row) * 512 + off];
  }
  // zero staging tiles (rows 4-15 stay zero = MFMA row padding) and state
  for (int i = tid * 8; i < 16 * 520; i += 256 * 8) {
    *(u16x8*)&At[i] = (u16x8)0;
    *(u16x8*)&Rt[i] = (u16x8)0;
    *(u16x8*)&Xt[i] = (u16x8)0;
  }
  if (tid < 128) { zbuf[tid] = 0.f; hbuf[tid] = 0.f; }
  __syncthreads();

  const int w = tid >> 6, l = tid & 63, cl = l & 15, kg = l >> 4;
  const int gate = w >> 1;             // phase A: waves 0,1 = Z; waves 2,3 = R
  const int lc16 = (w & 1) * 16;
  const int colA = role * 32 + lc16 + cl;
  const float biasA = (gate ? br : bz)[colA];
  const int lc16b = (w & 1) * 16;      // phase B (waves 0,1 only)
  const int colB = role * 32 + lc16b + cl;
  const float biasB = (w < 2) ? bn[colB] : 0.f;

  const size_t gofs = (size_t)g * 2048;
  u64* atdst = (u64*)&At[(tid >> 6) * 520 + (tid & 63) * 8];
  u64* xtdst = (u64*)&Xt[(tid >> 6) * 520 + (tid & 63) * 8];
  // rh-poll mapping (waves 2,3): tt=tid&127 -> row=tt>>5, 16-col chunk
  const int tt = tid & 127;
  const int prow = tt >> 5, pc16 = (tt & 31) * 16;
  u64* rtdst = (u64*)&Rt[prow * 520 + pc16];
  const unsigned short* WxA = Wx + (size_t)(gate * 512 + colA) * K;   // phase-A row
  const unsigned short* WxB = Wx + (size_t)(1024 + colB) * K;         // phase-B row

  for (int t = 0; t < SS; ++t) {
    // ---- stage x_t and h(t): all waits issued concurrently ----
    if (LAYER == 0) {
      u16x8 xreg;
      if (tid < 128) {  // issue x load first; latency hides under h-poll
        int j = tid >> 5, off = (tid & 31) * 8;
        xreg = *(const u16x8*)&Xe[((size_t)(t * 32) + 4 * g + j) * 256 + off];
      }
      u64 o[2];
      spin2((const u64*)(hx + (size_t)t * SLAB + gofs) + tid * 2, o, dead);
      atdst[0] = o[0]; atdst[1] = o[1];
      if (tid < 128) {
        int j = tid >> 5, off = (tid & 31) * 8;
        *(u16x8*)&Xt[j * 520 + off] = xreg;
      }
    } else {
      u64 o[4];
      spin22((const u64*)(hx0 + (size_t)(t + 1) * SLAB + gofs) + tid * 2,
             (const u64*)(hx + (size_t)t * SLAB + gofs) + tid * 2, o, dead);
      xtdst[0] = o[0]; xtdst[1] = o[1];
      atdst[0] = o[2]; atdst[1] = o[3];
    }
    __syncthreads();
    if (*(volatile int*)dead) break;

    // ---- phase A: acc = x@WxA + h@WhA ; Z -> zbuf | R -> publish rh NOW ----
    {
      v4f acc = {};
#pragma unroll
      for (int kc = 0; kc < K / 32; ++kc) {
        int ko = kc * 32 + kg * 8;
        v8ss a = *(const v8ss*)&Xt[cl * 520 + ko];
        v8ss b = *(const v8ss*)&WxA[ko];
        acc = MFMA16(a, b, acc);
      }
#pragma unroll
      for (int kc = 0; kc < 16; ++kc) {
        int ko = kc * 32 + kg * 8;
        v8ss a = *(const v8ss*)&At[cl * 520 + ko];
        v8ss b = *(const v8ss*)&Wt[(gate * 32 + lc16 + cl) * 520 + ko];
        acc = MFMA16(a, b, acc);
      }
      if (l < 16) {
        int lc = lc16 + cl;
#pragma unroll
        for (int j = 0; j < 4; ++j) {
          float pre = acc[j] + biasA;
          float gv = 1.f / (1.f + __expf(-pre));
          if (gate == 0) {
            zbuf[j * 32 + lc] = gv;
          } else {     // direct 2B publish from registers (no barrier first)
            astore16(&rhx[(size_t)t * SLAB + gofs + (size_t)j * 512 + colA],
                     f2bfp(gv * hbuf[j * 32 + lc]));
          }
        }
      }
    }
    // ---- waves 2,3: poll rh -> Rt  |  waves 0,1: phase-B x-proj overlap ----
    v4f accB = {};
    if (w >= 2) {
      u64 o[4];
      spin4((const u64*)(rhx + (size_t)t * SLAB + gofs + (size_t)prow * 512 + pc16), o, dead);
      rtdst[0] = o[0]; rtdst[1] = o[1]; rtdst[2] = o[2]; rtdst[3] = o[3];
    } else {
#pragma unroll
      for (int kc = 0; kc < K / 32; ++kc) {
        int ko = kc * 32 + kg * 8;
        v8ss a = *(const v8ss*)&Xt[cl * 520 + ko];
        v8ss b = *(const v8ss*)&WxB[ko];
        accB = MFMA16(a, b, accB);
      }
    }
    __syncthreads();
    if (*(volatile int*)dead) break;

    // ---- phase B: N gate + state update (waves 0,1); publish h' directly ----
    if (w < 2) {
#pragma unroll
      for (int kc = 0; kc < 16; ++kc) {
        int ko = kc * 32 + kg * 8;
        v8ss a = *(const v8ss*)&Rt[cl * 520 + ko];
        v8ss b = *(const v8ss*)&Wt[(64 + lc16b + cl) * 520 + ko];
        accB = MFMA16(a, b, accB);
      }
      if (l < 16) {
        int lc = lc16b + cl;
#pragma unroll
        for (int j = 0; j < 4; ++j) {
          float pre = accB[j] + biasB;
          float ht = 1.f - 2.f / (__expf(2.f * pre) + 1.f);   // overflow-safe tanh
          float z = zbuf[j * 32 + lc];
          float hn = (1.f - z) * hbuf[j * 32 + lc] + z * ht;
          hbuf[j * 32 + lc] = hn;
          astore16(&hx[(size_t)(t + 1) * SLAB + gofs + (size_t)j * 512 + colB],
                   f2bfp(hn));
        }
      }
    }
    __syncthreads();   // protects hbuf (A-readers) & tiles before next overwrite
  }

  // timeout: poison own chunks so consumers unblock & validation fails fast
  if (*(volatile int*)dead) {
    for (int s = tid; s < SS * 8; s += 256) {
      int t2 = s >> 3, c8 = s & 7;
      size_t o = gofs + role * 32 + c8 * 4;
#pragma unroll
      for (int j = 0; j < 4; ++j) {
        astore((u64*)(hx + (size_t)(t2 + 1) * SLAB + o + (size_t)j * 512), INF64);
        astore((u64*)(rhx + (size_t)t2 * SLAB + o + (size_t)j * 512), INF64);
      }
    }
  }
}

__global__ __launch_bounds__(256, 1) void gru_fused(
    const unsigned short* __restrict__ Wt0h, const unsigned short* __restrict__ Wt1h,
    const unsigned short* __restrict__ Wt0x, const unsigned short* __restrict__ Wt1x,
    const unsigned short* __restrict__ Xemb,
    unsigned short* hx0, unsigned short* rhx0,
    unsigned short* hx1, unsigned short* rhx1,
    const float* bz0, const float* br0, const float* bn0,
    const float* bz1, const float* br1, const float* bn1) {
  __shared__ unsigned short Wt[96 * 520];
  __shared__ unsigned short At[16 * 520];
  __shared__ unsigned short Rt[16 * 520];
  __shared__ unsigned short Xt[16 * 520];
  __shared__ float zbuf[128], hbuf[128];
  __shared__ int dead;
  const int tid = threadIdx.x;
  if (tid == 0) dead = 0;
  const int layer = blockIdx.x >> 7, id = blockIdx.x & 127;
  const int g = id >> 4, role = id & 15;
  if (layer == 0)
    gru_body<0>(g, role, tid, Wt0h, Wt0x, Xemb, nullptr, hx0, rhx0, bz0, br0, bn0,
                Wt, At, Rt, Xt, zbuf, hbuf, &dead);
  else
    gru_body<1>(g, role, tid, Wt1h, Wt1x, nullptr, hx0, hx1, rhx1, bz1, br1, bn1,
                Wt, At, Rt, Xt, zbuf, hbuf, &dead);
}

// ---------------------------------------------------------------------------
// fused FC + log_softmax: per block, rows m0..m0+31, all 128 cols.
// ---------------------------------------------------------------------------
__global__ __launch_bounds__(256) void fc_lsm_kernel(const unsigned short* __restrict__ Y1,
                                                     const unsigned short* __restrict__ WtFC,
                                                     const float* __restrict__ fcb,
                                                     float* __restrict__ out) {
  __shared__ float lout[32 * 128];
  int w = threadIdx.x >> 6, l = threadIdx.x & 63;
  int cl = l & 15, kg = l >> 4;
  int m0 = blockIdx.x * 32, n0 = w * 32;
  v4f acc[2][2] = {};
#pragma unroll
  for (int kc = 0; kc < 16; ++kc) {
    int ko = kc * 32 + kg * 8;
    v8ss a0 = *(const v8ss*)&Y1[(size_t)(m0 + cl) * 512 + ko];
    v8ss a1 = *(const v8ss*)&Y1[(size_t)(m0 + 16 + cl) * 512 + ko];
    v8ss b0 = *(const v8ss*)&WtFC[(size_t)(n0 + cl) * 512 + ko];
    v8ss b1 = *(const v8ss*)&WtFC[(size_t)(n0 + 16 + cl) * 512 + ko];
    acc[0][0] = MFMA16(a0, b0, acc[0][0]);
    acc[0][1] = MFMA16(a0, b1, acc[0][1]);
    acc[1][0] = MFMA16(a1, b0, acc[1][0]);
    acc[1][1] = MFMA16(a1, b1, acc[1][1]);
  }
#pragma unroll
  for (int mi = 0; mi < 2; ++mi)
#pragma unroll
    for (int ni = 0; ni < 2; ++ni) {
      int col = n0 + ni * 16 + cl;
      float bias = fcb[col];
#pragma unroll
      for (int r = 0; r < 4; ++r)
        lout[(mi * 16 + kg * 4 + r) * 128 + col] = acc[mi][ni][r] + bias;
    }
  __syncthreads();

  for (int rr = 0; rr < 8; ++rr) {
    int lr = w * 8 + rr;
    float a = lout[lr * 128 + l], b2 = lout[lr * 128 + 64 + l];
    float m = fmaxf(a, b2);
#pragma unroll
    for (int off = 32; off; off >>= 1) m = fmaxf(m, __shfl_xor(m, off));
    float s = __expf(a - m) + __expf(b2 - m);
#pragma unroll
    for (int off = 32; off; off >>= 1) s += __shfl_xor(s, off);
    float lse = m + logf(s);
    int mrow = m0 + lr, t = mrow >> 5, bb = mrow & 31;
    float* o = &out[((size_t)bb * SS + t) * 128];
    o[l] = a - lse;
    o[l + 64] = b2 - lse;
  }
}

// ---------------------------------------------------------------------------
extern "C" void kernel_launch(void* const* d_in, const int* in_sizes, int n_in,
                              void* d_out, int out_size, void* d_ws, size_t ws_size,
                              hipStream_t stream) {
  (void)in_sizes; (void)n_in; (void)out_size; (void)ws_size;
  const int*   tokens = (const int*)d_in[0];
  const float* emb    = (const float*)d_in[1];
  const float* l0Wz = (const float*)d_in[2];  const float* l0bz = (const float*)d_in[3];
  const float* l0Wr = (const float*)d_in[4];  const float* l0br = (const float*)d_in[5];
  const float* l0Wn = (const float*)d_in[6];  const float* l0bn = (const float*)d_in[7];
  const float* l1Wz = (const float*)d_in[8];  const float* l1bz = (const float*)d_in[9];
  const float* l1Wr = (const float*)d_in[10]; const float* l1br = (const float*)d_in[11];
  const float* l1Wn = (const float*)d_in[12]; const float* l1bn = (const float*)d_in[13];
  const float* fcW  = (const float*)d_in[14]; const float* fcb  = (const float*)d_in[15];

  char* ws = (char*)d_ws;
  unsigned short* hx0  = (unsigned short*)(ws + O_HX0);
  unsigned short* hx1  = (unsigned short*)(ws + O_HX1);
  unsigned short* rhx0 = (unsigned short*)(ws + O_RHX0);
  unsigned short* rhx1 = (unsigned short*)(ws + O_RHX1);
  unsigned short* Wt0x = (unsigned short*)(ws + O_WT0X);
  unsigned short* Wt0h = (unsigned short*)(ws + O_WT0H);
  unsigned short* Wt1x = (unsigned short*)(ws + O_WT1X);
  unsigned short* Wt1h = (unsigned short*)(ws + O_WT1H);
  unsigned short* WtFC = (unsigned short*)(ws + O_WTFC);
  unsigned short* Xemb = (unsigned short*)(ws + O_XEMB);

  // h slabs: slot 0 = zeros (h0), slots 1..512 = sentinel; rhx all sentinel
  hipMemsetAsync(hx0, 0x00, 32768, stream);
  hipMemsetAsync((char*)hx0 + 32768, 0x80, (size_t)SS * 32768, stream);
  hipMemsetAsync(hx1, 0x00, 32768, stream);
  hipMemsetAsync((char*)hx1 + 32768, 0x80, (size_t)SS * 32768, stream);
  hipMemsetAsync(rhx0, 0x80, (size_t)SS * 32768, stream);
  hipMemsetAsync(rhx1, 0x80, (size_t)SS * 32768, stream);

  prep_kernel<<<4096, 256, 0, stream>>>(l0Wz, l0Wr, l0Wn, l1Wz, l1Wr, l1Wn, fcW,
                                        Wt0x, Wt0h, Wt1x, Wt1h, WtFC);
  embed_kernel<<<MROWS, 256, 0, stream>>>(tokens, emb, Xemb);

  gru_fused<<<256, 256, 0, stream>>>(Wt0h, Wt1h, Wt0x, Wt1x, Xemb,
                                     hx0, rhx0, hx1, rhx1,
                                     l0bz, l0br, l0bn, l1bz, l1br, l1bn);

  fc_lsm_kernel<<<512, 256, 0, stream>>>(hx1 + SLAB, WtFC, fcb, (float*)d_out);
}

// Round 10
// 3120.392 us; speedup vs baseline: 1.1154x; 1.1154x over previous
//
#include <hip/hip_runtime.h>
#include <hip/hip_bf16.h>
#include <cstdint>
#include <cstddef>

// ---------------------------------------------------------------------------
// MultilayerGRU: emb-gather -> GRU(256->512) -> GRU(512->512) -> FC(512->128)
//                -> log_softmax.   B=32, S=512, DI=256, DH=512, DO=128
//
// Round-10: r8 pipeline + [col][batch] exchange slabs.
//  The MFMA C-fragment gives each lane (col, batches 0-3) -> with a
//  [col][batch] slab layout each lane's 4 gate outputs are ONE contiguous
//  u64: publish = single 8B agent-atomic store straight from registers
//  (no LDS staging barrier of r8, no torn 2B chunks of r9). Consumers
//  unpack chunks into [batch][col] LDS tiles via 4x ds_write_b16.
//  Polls are batched-concurrent (single RTT per wait). 3 barriers/step.
//  L1 also plain-stores Y1 in [m][c] for the FC kernel (dispatch-boundary
//  visibility, proven r1-r8). Cross-WG sync data: relaxed AGENT atomics only.
// ---------------------------------------------------------------------------

typedef short v8ss __attribute__((ext_vector_type(8)));     // 8 bf16 (4 VGPR)
typedef float v4f  __attribute__((ext_vector_type(4)));
typedef unsigned short u16x8 __attribute__((ext_vector_type(8)));
typedef unsigned long long u64;

#define MFMA16(a, b, c) __builtin_amdgcn_mfma_f32_16x16x32_bf16((a), (b), (c), 0, 0, 0)

__device__ __forceinline__ unsigned short f2bf(float f) {
  union { float f; unsigned u; } v; v.f = f;
  unsigned r = v.u + 0x7fffu + ((v.u >> 16) & 1u);   // RNE
  return (unsigned short)(r >> 16);
}
// published values must never equal the sentinel bf16 pattern 0x8080
__device__ __forceinline__ unsigned short f2bfp(float f) {
  unsigned short h = f2bf(f);
  return (h == 0x8080u) ? (unsigned short)0x8081u : h;   // |delta| ~ 1e-38
}
__device__ __forceinline__ float bf2f(unsigned short h) {
  union { unsigned u; float f; } v; v.u = ((unsigned)h) << 16; return v.f;
}

#define S64   0x8080808080808080ull
#define INF64 0x7F807F807F807F80ull
#define POLL_LIM 65536

__device__ __forceinline__ u64 aload(const u64* p) {
  return __hip_atomic_load(p, __ATOMIC_RELAXED, __HIP_MEMORY_SCOPE_AGENT);
}
__device__ __forceinline__ void astore(u64* p, u64 v) {
  __hip_atomic_store(p, v, __ATOMIC_RELAXED, __HIP_MEMORY_SCOPE_AGENT);
}
// chunks are written atomically as 8B -> whole-chunk sentinel compare.
// all loads of a wait are issued before any check (single fabric RTT).
__device__ __forceinline__ void spin2(const u64* p, u64* o, int* dead) {
  u64 a = aload(p), b = aload(p + 1);
  int it = 0;
  while ((a == S64) | (b == S64)) {
    if (*(volatile int*)dead) break;
    if (++it > POLL_LIM) { *(volatile int*)dead = 1; break; }
    if (it > 4) __builtin_amdgcn_s_sleep(1);
    a = aload(p); b = aload(p + 1);
  }
  o[0] = a; o[1] = b;
}
__device__ __forceinline__ void spin4(const u64* p, u64* o, int* dead) {
  u64 a = aload(p), b = aload(p + 1), c = aload(p + 2), d = aload(p + 3);
  int it = 0;
  while ((a == S64) | (b == S64) | (c == S64) | (d == S64)) {
    if (*(volatile int*)dead) break;
    if (++it > POLL_LIM) { *(volatile int*)dead = 1; break; }
    if (it > 4) __builtin_amdgcn_s_sleep(1);
    a = aload(p); b = aload(p + 1); c = aload(p + 2); d = aload(p + 3);
  }
  o[0] = a; o[1] = b; o[2] = c; o[3] = d;
}
__device__ __forceinline__ void spin22(const u64* p, const u64* q, u64* o, int* dead) {
  u64 a = aload(p), b = aload(p + 1), c = aload(q), d = aload(q + 1);
  int it = 0;
  while ((a == S64) | (b == S64) | (c == S64) | (d == S64)) {
    if (*(volatile int*)dead) break;
    if (++it > POLL_LIM) { *(volatile int*)dead = 1; break; }
    if (it > 4) __builtin_amdgcn_s_sleep(1);
    a = aload(p); b = aload(p + 1); c = aload(q); d = aload(q + 1);
  }
  o[0] = a; o[1] = b; o[2] = c; o[3] = d;
}
// unpack one [col][batch] chunk into a [batch][col] LDS tile (pitch 520)
__device__ __forceinline__ void chunk2lds(unsigned short* base, int col, u64 v) {
  base[col]            = (unsigned short)v;
  base[520 + col]      = (unsigned short)(v >> 16);
  base[2 * 520 + col]  = (unsigned short)(v >> 32);
  base[3 * 520 + col]  = (unsigned short)(v >> 48);
}

// ----- sizes -----
#define BB   32
#define SS   512
#define DI   256
#define DH   512
#define DO   128
#define MROWS (BB * SS)          // 16384, row index = t*32 + b
#define SLAB 16384               // elems per time-slot: 8 groups x [512 col][4 batch]

// ----- ws offsets (bytes); total ~98 MB (<= proven 106.4 MB) -----
#define O_HX0   0                              // [513][SLAB] bf16, [col][batch] groups
#define O_HX1   16809984
#define O_RHX0  33619968                       // [512][SLAB] bf16
#define O_RHX1  50397184
#define O_Y1    67174400                       // [16384][512] bf16, [m][c]
#define O_WT0X  (O_Y1 + (size_t)MROWS*DH*2)    // [1536][256] bf16 (streamed)
#define O_WT0H  (O_WT0X + 1536*256*2)          // [16][96][512] bf16
#define O_WT1X  (O_WT0H + 16*96*512*2)         // [1536][512] bf16 (streamed)
#define O_WT1H  (O_WT1X + 1536*512*2)          // [16][96][512] bf16
#define O_WTFC  (O_WT1H + 16*96*512*2)         // [128][512] bf16
#define O_XEMB  (O_WTFC + 128*512*2)           // [16384][256] bf16

// ---------------------------------------------------------------------------
// weight repack: f32 -> bf16 transposed layouts
// ---------------------------------------------------------------------------
__global__ void prep_kernel(const float* __restrict__ l0Wz, const float* __restrict__ l0Wr,
                            const float* __restrict__ l0Wn,
                            const float* __restrict__ l1Wz, const float* __restrict__ l1Wr,
                            const float* __restrict__ l1Wn,
                            const float* __restrict__ fcW,
                            unsigned short* __restrict__ Wt0x, unsigned short* __restrict__ Wt0h,
                            unsigned short* __restrict__ Wt1x, unsigned short* __restrict__ Wt1h,
                            unsigned short* __restrict__ WtFC) {
  const int n0 = 1536 * 256;        // Wt0x
  const int n1 = 16 * 96 * 512;     // Wt0h
  const int n2 = 1536 * 512;        // Wt1x
  const int n3 = 16 * 96 * 512;     // Wt1h
  const int n4 = 128 * 512;         // WtFC
  const int total = n0 + n1 + n2 + n3 + n4;
  for (int i = blockIdx.x * 256 + threadIdx.x; i < total; i += gridDim.x * 256) {
    int j = i;
    if (j < n0) {  // Wt0x[gcol][k] = l0_W{g}[k][c]
      int gcol = j / 256, k = j % 256, g = gcol >> 9, c = gcol & 511;
      const float* W = g == 0 ? l0Wz : (g == 1 ? l0Wr : l0Wn);
      Wt0x[j] = f2bf(W[k * 512 + c]); continue;
    }
    j -= n0;
    if (j < n1) {  // Wt0h[r][row][k] = l0_W{g(row)}[256+k][r*32 + (row&31)]
      int r = j / (96 * 512), rem = j % (96 * 512), row = rem / 512, k = rem % 512;
      int g = row >> 5, c = r * 32 + (row & 31);
      const float* W = g == 0 ? l0Wz : (g == 1 ? l0Wr : l0Wn);
      Wt0h[j] = f2bf(W[(256 + k) * 512 + c]); continue;
    }
    j -= n1;
    if (j < n2) {  // Wt1x[gcol][k] = l1_W{g}[k][c]
      int gcol = j / 512, k = j % 512, g = gcol >> 9, c = gcol & 511;
      const float* W = g == 0 ? l1Wz : (g == 1 ? l1Wr : l1Wn);
      Wt1x[j] = f2bf(W[k * 512 + c]); continue;
    }
    j -= n2;
    if (j < n3) {  // Wt1h[r][row][k] = l1_W{g(row)}[512+k][r*32 + (row&31)]
      int r = j / (96 * 512), rem = j % (96 * 512), row = rem / 512, k = rem % 512;
      int g = row >> 5, c = r * 32 + (row & 31);
      const float* W = g == 0 ? l1Wz : (g == 1 ? l1Wr : l1Wn);
      Wt1h[j] = f2bf(W[(512 + k) * 512 + c]); continue;
    }
    j -= n3;
    { int c = j / 512, k = j % 512; WtFC[j] = f2bf(fcW[k * 128 + c]); }
  }
}

// ---------------------------------------------------------------------------
// embedding gather
// ---------------------------------------------------------------------------
__global__ void embed_kernel(const int* __restrict__ tokens, const float* __restrict__ emb,
                             unsigned short* __restrict__ Xemb) {
  int r = blockIdx.x;            // 0..16383  (t-major)
  int c = threadIdx.x;           // 0..255
  int t = r >> 5, b = r & 31;
  int tok = tokens[b * SS + t];
  Xemb[(size_t)r * DI + c] = f2bf(emb[(size_t)tok * DI + c]);
}

// ---------------------------------------------------------------------------
// fused pipelined GRU body (one layer instance per WG).
// group g owns batches 4g..4g+3; role owns h-cols 32r..32r+31.
// exchange slabs are [col][batch] per group (chunk = u64 = 4 batches of a col).
// ---------------------------------------------------------------------------
template <int LAYER>
__device__ __forceinline__ void gru_body(
    const int g, const int role, const int tid,
    const unsigned short* __restrict__ WtH,   // [16][96][512]
    const unsigned short* __restrict__ Wx,    // [1536][K]
    const unsigned short* __restrict__ Xe,    // Xemb (L0 only)
    unsigned short* hx0,                      // x-source slabs (L1 only)
    unsigned short* hx, unsigned short* rhx,
    unsigned short* Y1,                       // [m][c] output (L1 only)
    const float* __restrict__ bz, const float* __restrict__ br,
    const float* __restrict__ bn,
    unsigned short* Wt, unsigned short* At, unsigned short* Rt, unsigned short* Xt,
    float* zbuf, float* hbuf, int* dead) {
  constexpr int K = LAYER ? 512 : 256;

  // recurrent-weight slice -> LDS (96 rows x 512)
  for (int ch = tid; ch < 96 * 64; ch += 256) {
    int row = ch >> 6, off = (ch & 63) * 8;
    *(u16x8*)&Wt[row * 520 + off] = *(const u16x8*)&WtH[((size_t)role * 96 + row) * 512 + off];
  }
  // zero staging tiles (rows 4-15 stay zero = MFMA row padding) and state
  for (int i = tid * 8; i < 16 * 520; i += 256 * 8) {
    *(u16x8*)&At[i] = (u16x8)0;
    *(u16x8*)&Rt[i] = (u16x8)0;
    *(u16x8*)&Xt[i] = (u16x8)0;
  }
  if (tid < 128) { zbuf[tid] = 0.f; hbuf[tid] = 0.f; }
  __syncthreads();

  const int w = tid >> 6, l = tid & 63, cl = l & 15, kg = l >> 4;
  const int gate = w >> 1;             // phase A: waves 0,1 = Z; waves 2,3 = R
  const int lc16 = (w & 1) * 16;
  const int colA = role * 32 + lc16 + cl;
  const float biasA = (gate ? br : bz)[colA];
  const int lc16b = (w & 1) * 16;      // phase B (waves 0,1 only)
  const int colB = role * 32 + lc16b + cl;
  const float biasB = (w < 2) ? bn[colB] : 0.f;

  const size_t gofs = (size_t)g * 2048;          // group slab: [512 col][4 batch]
  // rh-poll mapping (waves 2,3): tt=tid-128 -> cols 4tt..4tt+3
  const int tt = tid & 127;
  const unsigned short* WxA = Wx + (size_t)(gate * 512 + colA) * K;   // phase-A row
  const unsigned short* WxB = Wx + (size_t)(1024 + colB) * K;         // phase-B row

  for (int t = 0; t < SS; ++t) {
    // ---- stage x_t and h(t): all waits issued concurrently ----
    if (LAYER == 0) {
      u16x8 xreg;
      if (tid < 128) {  // issue x load first; latency hides under h-poll
        int j = tid >> 5, off = (tid & 31) * 8;
        xreg = *(const u16x8*)&Xe[((size_t)(t * 32) + 4 * g + j) * 256 + off];
      }
      u64 o[2];
      spin2((const u64*)(hx + (size_t)t * SLAB + gofs) + tid * 2, o, dead);
      chunk2lds(At, tid * 2, o[0]);
      chunk2lds(At, tid * 2 + 1, o[1]);
      if (tid < 128) {
        int j = tid >> 5, off = (tid & 31) * 8;
        *(u16x8*)&Xt[j * 520 + off] = xreg;
      }
    } else {
      u64 o[4];
      spin22((const u64*)(hx0 + (size_t)(t + 1) * SLAB + gofs) + tid * 2,
             (const u64*)(hx + (size_t)t * SLAB + gofs) + tid * 2, o, dead);
      chunk2lds(Xt, tid * 2, o[0]);
      chunk2lds(Xt, tid * 2 + 1, o[1]);
      chunk2lds(At, tid * 2, o[2]);
      chunk2lds(At, tid * 2 + 1, o[3]);
    }
    __syncthreads();
    if (*(volatile int*)dead) break;

    // ---- phase A: acc = x@WxA + h@WhA ; Z -> zbuf | R -> pack+publish 8B ----
    {
      v4f acc = {};
#pragma unroll
      for (int kc = 0; kc < K / 32; ++kc) {
        int ko = kc * 32 + kg * 8;
        v8ss a = *(const v8ss*)&Xt[cl * 520 + ko];
        v8ss b = *(const v8ss*)&WxA[ko];
        acc = MFMA16(a, b, acc);
      }
#pragma unroll
      for (int kc = 0; kc < 16; ++kc) {
        int ko = kc * 32 + kg * 8;
        v8ss a = *(const v8ss*)&At[cl * 520 + ko];
        v8ss b = *(const v8ss*)&Wt[(gate * 32 + lc16 + cl) * 520 + ko];
        acc = MFMA16(a, b, acc);
      }
      if (l < 16) {
        if (gate == 0) {
#pragma unroll
          for (int j = 0; j < 4; ++j) {
            float pre = acc[j] + biasA;
            zbuf[j * 32 + lc16 + cl] = 1.f / (1.f + __expf(-pre));
          }
        } else {   // R: pack 4 batches of this col into one u64, publish now
          u64 pk = 0;
#pragma unroll
          for (int j = 0; j < 4; ++j) {
            float pre = acc[j] + biasA;
            float gv = 1.f / (1.f + __expf(-pre));
            pk |= (u64)f2bfp(gv * hbuf[j * 32 + lc16 + cl]) << (16 * j);
          }
          astore((u64*)(rhx + (size_t)t * SLAB + gofs) + colA, pk);
        }
      }
    }
    // ---- waves 2,3: poll rh -> Rt  |  waves 0,1: phase-B x-proj overlap ----
    v4f accB = {};
    if (w >= 2) {
      u64 o[4];
      spin4((const u64*)(rhx + (size_t)t * SLAB + gofs) + tt * 4, o, dead);
      chunk2lds(Rt, tt * 4, o[0]);
      chunk2lds(Rt, tt * 4 + 1, o[1]);
      chunk2lds(Rt, tt * 4 + 2, o[2]);
      chunk2lds(Rt, tt * 4 + 3, o[3]);
    } else {
#pragma unroll
      for (int kc = 0; kc < K / 32; ++kc) {
        int ko = kc * 32 + kg * 8;
        v8ss a = *(const v8ss*)&Xt[cl * 520 + ko];
        v8ss b = *(const v8ss*)&WxB[ko];
        accB = MFMA16(a, b, accB);
      }
    }
    __syncthreads();
    if (*(volatile int*)dead) break;

    // ---- phase B: N gate + state update (waves 0,1); pack+publish h' ----
    if (w < 2) {
#pragma unroll
      for (int kc = 0; kc < 16; ++kc) {
        int ko = kc * 32 + kg * 8;
        v8ss a = *(const v8ss*)&Rt[cl * 520 + ko];
        v8ss b = *(const v8ss*)&Wt[(64 + lc16b + cl) * 520 + ko];
        accB = MFMA16(a, b, accB);
      }
      if (l < 16) {
        int lc = lc16b + cl;
        u64 pk = 0;
        unsigned short hv[4];
#pragma unroll
        for (int j = 0; j < 4; ++j) {
          float pre = accB[j] + biasB;
          float ht = 1.f - 2.f / (__expf(2.f * pre) + 1.f);   // overflow-safe tanh
          float z = zbuf[j * 32 + lc];
          float hn = (1.f - z) * hbuf[j * 32 + lc] + z * ht;
          hbuf[j * 32 + lc] = hn;
          hv[j] = f2bfp(hn);
          pk |= (u64)hv[j] << (16 * j);
        }
        astore((u64*)(hx + (size_t)(t + 1) * SLAB + gofs) + colB, pk);
        if (LAYER == 1) {   // [m][c] output for FC (plain stores, off-path)
#pragma unroll
          for (int j = 0; j < 4; ++j)
            Y1[((size_t)(t * 32) + 4 * g + j) * 512 + colB] = hv[j];
        }
      }
    }
    __syncthreads();   // protects hbuf (A-readers) & tiles before next overwrite
  }

  // timeout: poison own chunks so consumers unblock & validation fails fast
  if (*(volatile int*)dead) {
    for (int s = tid; s < SS * 32; s += 256) {
      int t2 = s >> 5, c = role * 32 + (s & 31);
      astore((u64*)(hx + (size_t)(t2 + 1) * SLAB + gofs) + c, INF64);
      astore((u64*)(rhx + (size_t)t2 * SLAB + gofs) + c, INF64);
    }
  }
}

__global__ __launch_bounds__(256, 1) void gru_fused(
    const unsigned short* __restrict__ Wt0h, const unsigned short* __restrict__ Wt1h,
    const unsigned short* __restrict__ Wt0x, const unsigned short* __restrict__ Wt1x,
    const unsigned short* __restrict__ Xemb,
    unsigned short* hx0, unsigned short* rhx0,
    unsigned short* hx1, unsigned short* rhx1,
    unsigned short* Y1,
    const float* bz0, const float* br0, const float* bn0,
    const float* bz1, const float* br1, const float* bn1) {
  __shared__ unsigned short Wt[96 * 520];
  __shared__ unsigned short At[16 * 520];
  __shared__ unsigned short Rt[16 * 520];
  __shared__ unsigned short Xt[16 * 520];
  __shared__ float zbuf[128], hbuf[128];
  __shared__ int dead;
  const int tid = threadIdx.x;
  if (tid == 0) dead = 0;
  const int layer = blockIdx.x >> 7, id = blockIdx.x & 127;
  const int g = id >> 4, role = id & 15;
  if (layer == 0)
    gru_body<0>(g, role, tid, Wt0h, Wt0x, Xemb, nullptr, hx0, rhx0, nullptr,
                bz0, br0, bn0, Wt, At, Rt, Xt, zbuf, hbuf, &dead);
  else
    gru_body<1>(g, role, tid, Wt1h, Wt1x, nullptr, hx0, hx1, rhx1, Y1,
                bz1, br1, bn1, Wt, At, Rt, Xt, zbuf, hbuf, &dead);
}

// ---------------------------------------------------------------------------
// fused FC + log_softmax: per block, rows m0..m0+31, all 128 cols.
// ---------------------------------------------------------------------------
__global__ __launch_bounds__(256) void fc_lsm_kernel(const unsigned short* __restrict__ Y1,
                                                     const unsigned short* __restrict__ WtFC,
                                                     const float* __restrict__ fcb,
                                                     float* __restrict__ out) {
  __shared__ float lout[32 * 128];
  int w = threadIdx.x >> 6, l = threadIdx.x & 63;
  int cl = l & 15, kg = l >> 4;
  int m0 = blockIdx.x * 32, n0 = w * 32;
  v4f acc[2][2] = {};
#pragma unroll
  for (int kc = 0; kc < 16; ++kc) {
    int ko = kc * 32 + kg * 8;
    v8ss a0 = *(const v8ss*)&Y1[(size_t)(m0 + cl) * 512 + ko];
    v8ss a1 = *(const v8ss*)&Y1[(size_t)(m0 + 16 + cl) * 512 + ko];
    v8ss b0 = *(const v8ss*)&WtFC[(size_t)(n0 + cl) * 512 + ko];
    v8ss b1 = *(const v8ss*)&WtFC[(size_t)(n0 + 16 + cl) * 512 + ko];
    acc[0][0] = MFMA16(a0, b0, acc[0][0]);
    acc[0][1] = MFMA16(a0, b1, acc[0][1]);
    acc[1][0] = MFMA16(a1, b0, acc[1][0]);
    acc[1][1] = MFMA16(a1, b1, acc[1][1]);
  }
#pragma unroll
  for (int mi = 0; mi < 2; ++mi)
#pragma unroll
    for (int ni = 0; ni < 2; ++ni) {
      int col = n0 + ni * 16 + cl;
      float bias = fcb[col];
#pragma unroll
      for (int r = 0; r < 4; ++r)
        lout[(mi * 16 + kg * 4 + r) * 128 + col] = acc[mi][ni][r] + bias;
    }
  __syncthreads();

  for (int rr = 0; rr < 8; ++rr) {
    int lr = w * 8 + rr;
    float a = lout[lr * 128 + l], b2 = lout[lr * 128 + 64 + l];
    float m = fmaxf(a, b2);
#pragma unroll
    for (int off = 32; off; off >>= 1) m = fmaxf(m, __shfl_xor(m, off));
    float s = __expf(a - m) + __expf(b2 - m);
#pragma unroll
    for (int off = 32; off; off >>= 1) s += __shfl_xor(s, off);
    float lse = m + logf(s);
    int mrow = m0 + lr, t = mrow >> 5, bb = mrow & 31;
    float* o = &out[((size_t)bb * SS + t) * 128];
    o[l] = a - lse;
    o[l + 64] = b2 - lse;
  }
}

// ---------------------------------------------------------------------------
extern "C" void kernel_launch(void* const* d_in, const int* in_sizes, int n_in,
                              void* d_out, int out_size, void* d_ws, size_t ws_size,
                              hipStream_t stream) {
  (void)in_sizes; (void)n_in; (void)out_size; (void)ws_size;
  const int*   tokens = (const int*)d_in[0];
  const float* emb    = (const float*)d_in[1];
  const float* l0Wz = (const float*)d_in[2];  const float* l0bz = (const float*)d_in[3];
  const float* l0Wr = (const float*)d_in[4];  const float* l0br = (const float*)d_in[5];
  const float* l0Wn = (const float*)d_in[6];  const float* l0bn = (const float*)d_in[7];
  const float* l1Wz = (const float*)d_in[8];  const float* l1bz = (const float*)d_in[9];
  const float* l1Wr = (const float*)d_in[10]; const float* l1br = (const float*)d_in[11];
  const float* l1Wn = (const float*)d_in[12]; const float* l1bn = (const float*)d_in[13];
  const float* fcW  = (const float*)d_in[14]; const float* fcb  = (const float*)d_in[15];

  char* ws = (char*)d_ws;
  unsigned short* hx0  = (unsigned short*)(ws + O_HX0);
  unsigned short* hx1  = (unsigned short*)(ws + O_HX1);
  unsigned short* rhx0 = (unsigned short*)(ws + O_RHX0);
  unsigned short* rhx1 = (unsigned short*)(ws + O_RHX1);
  unsigned short* Y1   = (unsigned short*)(ws + O_Y1);
  unsigned short* Wt0x = (unsigned short*)(ws + O_WT0X);
  unsigned short* Wt0h = (unsigned short*)(ws + O_WT0H);
  unsigned short* Wt1x = (unsigned short*)(ws + O_WT1X);
  unsigned short* Wt1h = (unsigned short*)(ws + O_WT1H);
  unsigned short* WtFC = (unsigned short*)(ws + O_WTFC);
  unsigned short* Xemb = (unsigned short*)(ws + O_XEMB);

  // h slabs: slot 0 = zeros (h0), slots 1..512 = sentinel; rhx all sentinel
  hipMemsetAsync(hx0, 0x00, 32768, stream);
  hipMemsetAsync((char*)hx0 + 32768, 0x80, (size_t)SS * 32768, stream);
  hipMemsetAsync(hx1, 0x00, 32768, stream);
  hipMemsetAsync((char*)hx1 + 32768, 0x80, (size_t)SS * 32768, stream);
  hipMemsetAsync(rhx0, 0x80, (size_t)SS * 32768, stream);
  hipMemsetAsync(rhx1, 0x80, (size_t)SS * 32768, stream);

  prep_kernel<<<4096, 256, 0, stream>>>(l0Wz, l0Wr, l0Wn, l1Wz, l1Wr, l1Wn, fcW,
                                        Wt0x, Wt0h, Wt1x, Wt1h, WtFC);
  embed_kernel<<<MROWS, 256, 0, stream>>>(tokens, emb, Xemb);

  gru_fused<<<256, 256, 0, stream>>>(Wt0h, Wt1h, Wt0x, Wt1x, Xemb,
                                     hx0, rhx0, hx1, rhx1, Y1,
                                     l0bz, l0br, l0bn, l1bz, l1br, l1bn);

  fc_lsm_kernel<<<512, 256, 0, stream>>>(Y1, WtFC, fcb, (float*)d_out);
}